// Round 13
// baseline (1728.771 us; speedup 1.0000x reference)
//
#include <hip/hip_runtime.h>
#include <hip/hip_bf16.h>
#include <math.h>

// Problem constants
#define BB 4
#define SS 1024
#define DD 768
#define HH 12
#define LL 6
#define FF 3072
#define VV 32000
#define DK 64
#define MM (BB * SS)   // 4096 rows

typedef __attribute__((ext_vector_type(8))) short s8v;   // 8 bf16 (4 VGPRs)
typedef __attribute__((ext_vector_type(4))) float f4v;   // 4 fp32 acc

__device__ inline unsigned short f2bf_bits(float f) {
    unsigned u = __builtin_bit_cast(unsigned, f);
    unsigned r = (u + 0x7fffu + ((u >> 16) & 1u)) >> 16;
    return (unsigned short)r;
}

__device__ inline void gl_lds16(const void* g, void* l) {
    __builtin_amdgcn_global_load_lds((const __attribute__((address_space(1))) void*)g,
                                     (__attribute__((address_space(3))) void*)l, 16, 0, 0);
}

// ---------------------------------------------------------------------------
__global__ void embed_kernel(const int* __restrict__ tokens,
                             const float* __restrict__ emb,
                             float* __restrict__ x) {
    const int row = blockIdx.x;
    const int s = row % SS;
    const int tok = tokens[row];
    const float* er = emb + (size_t)tok * DD;
    float* xr = x + (size_t)row * DD;
    const float neg_ln_base = -logf(10000.0f) / (float)DD;
    for (int d = threadIdx.x; d < DD; d += blockDim.x) {
        int i2 = d & ~1;
        float div = expf((float)i2 * neg_ln_base);
        float ang = (float)s * div;
        float pe = (d & 1) ? cosf(ang) : sinf(ang);
        xr[d] = er[d] + pe;
    }
}

// ---------------------------------------------------------------------------
// LayerNorm: one WAVE per row (4 rows / 256-block), shuffle-only reduce.
template <int OUTBF>
__global__ __launch_bounds__(256) void ln_kernel(const float* __restrict__ x,
                                                 const float* __restrict__ g,
                                                 const float* __restrict__ b,
                                                 void* __restrict__ outp) {
    const int row = blockIdx.x * 4 + (threadIdx.x >> 6);
    const int lane = threadIdx.x & 63;
    const float* xr = x + (size_t)row * DD;

    float4 v[3];
    float s = 0.f, s2 = 0.f;
    #pragma unroll
    for (int j = 0; j < 3; j++) {
        v[j] = *(const float4*)(xr + j * 256 + lane * 4);
        s  += v[j].x + v[j].y + v[j].z + v[j].w;
        s2 += v[j].x * v[j].x + v[j].y * v[j].y + v[j].z * v[j].z + v[j].w * v[j].w;
    }
    #pragma unroll
    for (int off = 32; off; off >>= 1) {
        s  += __shfl_xor(s, off);
        s2 += __shfl_xor(s2, off);
    }
    const float mu = s / (float)DD;
    const float var = s2 / (float)DD - mu * mu;
    const float r = rsqrtf(var + 1e-5f);

    #pragma unroll
    for (int j = 0; j < 3; j++) {
        const int c = j * 256 + lane * 4;
        const float4 gv = *(const float4*)(g + c);
        const float4 bv = *(const float4*)(b + c);
        float o0 = (v[j].x - mu) * r * gv.x + bv.x;
        float o1 = (v[j].y - mu) * r * gv.y + bv.y;
        float o2 = (v[j].z - mu) * r * gv.z + bv.z;
        float o3 = (v[j].w - mu) * r * gv.w + bv.w;
        if (OUTBF) {
            ushort4 o;
            o.x = f2bf_bits(o0); o.y = f2bf_bits(o1);
            o.z = f2bf_bits(o2); o.w = f2bf_bits(o3);
            *(ushort4*)((unsigned short*)outp + (size_t)row * DD + c) = o;
        } else {
            float4 o = {o0, o1, o2, o3};
            *(float4*)((float*)outp + (size_t)row * DD + c) = o;
        }
    }
}

// ---------------------------------------------------------------------------
// ALL-layer weight prep in one launch: 6 layers x 1728 tiles.
__global__ __launch_bounds__(256) void prep_kernel(const float* __restrict__ Wq,
                                                   const float* __restrict__ Wk,
                                                   const float* __restrict__ Wv,
                                                   const float* __restrict__ Wo,
                                                   const float* __restrict__ W1,
                                                   const float* __restrict__ W2,
                                                   unsigned short* __restrict__ wqkvT,
                                                   unsigned short* __restrict__ woT,
                                                   unsigned short* __restrict__ w1T,
                                                   unsigned short* __restrict__ w2T) {
    const size_t DxD = (size_t)DD * DD, DxF = (size_t)DD * FF;
    const int lid = blockIdx.x / 1728;
    const int id  = blockIdx.x % 1728;
    const float* src; unsigned short* dst; int R, C, t;
    if (id < 432)       { int seg = id / 144; t = id % 144;
                          src = (seg == 0 ? Wq : seg == 1 ? Wk : Wv) + lid * DxD;
                          dst = wqkvT + lid * 3 * DxD + (size_t)seg * DxD; R = DD; C = DD; }
    else if (id < 576)  { t = id - 432; src = Wo + lid * DxD; dst = woT + lid * DxD; R = DD; C = DD; }
    else if (id < 1152) { t = id - 576;  src = W1 + lid * DxF; dst = w1T + lid * DxF; R = DD; C = FF; }
    else                { t = id - 1152; src = W2 + lid * DxF; dst = w2T + lid * DxF; R = FF; C = DD; }
    const int tilesC = C / 64;
    const int r0 = (t / tilesC) * 64, c0 = (t % tilesC) * 64;
    __shared__ float tb[64][65];
    const int lr = threadIdx.x >> 6, lc = threadIdx.x & 63;
    #pragma unroll
    for (int it = 0; it < 16; ++it) {
        int r = it * 4 + lr;
        tb[r][lc] = src[(size_t)(r0 + r) * C + c0 + lc];
    }
    __syncthreads();
    #pragma unroll
    for (int it = 0; it < 16; ++it) {
        int c = it * 4 + lr;
        dst[(size_t)(c0 + c) * R + r0 + lc] = f2bf_bits(tb[lc][c]);
    }
}

__global__ __launch_bounds__(256) void conv_kernel(const float* __restrict__ in,
                                                   unsigned short* __restrict__ out,
                                                   long n4) {
    long i = (long)blockIdx.x * 256 + threadIdx.x;
    if (i < n4) {
        float4 v = ((const float4*)in)[i];
        ushort4 o;
        o.x = f2bf_bits(v.x); o.y = f2bf_bits(v.y);
        o.z = f2bf_bits(v.z); o.w = f2bf_bits(v.w);
        ((ushort4*)out)[i] = o;
    }
}

// ---------------------------------------------------------------------------
// bf16 MFMA GEMM, BK=32, DOUBLE-BUFFERED LDS (round-11 proven).
// OUTMODE: 0 fp32 [M,N]; 1 bf16 [M,N]; 3 fused-QKV split (needs BM=BN=128).
// OUTMODE 3: q output pre-scaled by 1/sqrt(dk)=0.125 (consumed only by fattn).
template <int BM, int BN, int WGM, int WGN, int ACT, int RES, int OUTMODE>
__global__ __launch_bounds__(256) void gemm_mfma(const unsigned short* __restrict__ A,
                                                 const unsigned short* __restrict__ Bt,
                                                 const float* __restrict__ bias,
                                                 const float* res,
                                                 void* Cout, int M, int N, int K,
                                                 const float* biasK, const float* biasV,
                                                 unsigned short* kout, unsigned short* vtout) {
    __shared__ unsigned short As[2][BM * 32];
    __shared__ unsigned short Bs[2][BN * 32];
    constexpr int MF = (BM / WGM) / 16;
    constexpr int NF = (BN / WGN) / 16;
    const int tid = threadIdx.x;
    const int bm = blockIdx.y * BM, bn = blockIdx.x * BN;
    const int lane = tid & 63;
    const int wave = tid >> 6;
    const int wr = (wave / WGN) * (BM / WGM);
    const int wc = (wave % WGN) * (BN / WGN);

    f4v acc[MF][NF];
    #pragma unroll
    for (int i = 0; i < MF; i++)
        #pragma unroll
        for (int j = 0; j < NF; j++)
            acc[i][j] = (f4v){0.f, 0.f, 0.f, 0.f};

    const int arow = tid >> 2;        // 0..63
    const int acol = (tid & 3) * 8;
    const int fr = lane & 15;
    const int fk = (lane >> 4) * 8;

    auto stage = [&](int d, int kt) {
        const int k0 = kt * 32;
        #pragma unroll
        for (int i = 0; i < BM / 64; i++)
            gl_lds16(A + (size_t)(bm + i * 64 + arow) * K + k0 + acol,
                     (char*)(&As[d][0]) + i * 4096 + tid * 16);
        #pragma unroll
        for (int i = 0; i < BN / 64; i++)
            gl_lds16(Bt + (size_t)(bn + i * 64 + arow) * K + k0 + acol,
                     (char*)(&Bs[d][0]) + i * 4096 + tid * 16);
    };

    const int nkt = K / 32;
    stage(0, 0);
    __syncthreads();

    for (int t = 0; t < nkt; ++t) {
        const int cur = t & 1;
        if (t + 1 < nkt) stage(cur ^ 1, t + 1);

        const unsigned short* Ac = &As[cur][0];
        const unsigned short* Bc = &Bs[cur][0];
        s8v af[MF], bf[NF];
        #pragma unroll
        for (int i = 0; i < MF; i++)
            af[i] = *(const s8v*)(Ac + (wr + i * 16 + fr) * 32 + fk);
        #pragma unroll
        for (int j = 0; j < NF; j++)
            bf[j] = *(const s8v*)(Bc + (wc + j * 16 + fr) * 32 + fk);
        #pragma unroll
        for (int i = 0; i < MF; i++)
            #pragma unroll
            for (int j = 0; j < NF; j++)
                acc[i][j] = __builtin_amdgcn_mfma_f32_16x16x32_bf16(af[i], bf[j], acc[i][j], 0, 0, 0);
        __syncthreads();
    }

    const int r0 = bm + wr + (lane >> 4) * 4;
    const int c0 = bn + wc + fr;
    #pragma unroll
    for (int i = 0; i < MF; i++) {
        const int rb = r0 + i * 16;
        #pragma unroll
        for (int j = 0; j < NF; j++) {
            const int c = c0 + j * 16;
            if (OUTMODE == 3) {
                const int seg = (c >= 1536) ? 2 : (c >= 768 ? 1 : 0);
                const int cc = c - seg * 768;
                const float bb = (seg == 0 ? bias[cc] : seg == 1 ? biasK[cc] : biasV[cc]);
                if (seg < 2) {
                    unsigned short* dst = (seg == 0 ? (unsigned short*)Cout : kout);
                    const float sc = (seg == 0) ? 0.125f : 1.0f;   // pre-scale q by 1/sqrt(dk)
                    #pragma unroll
                    for (int q = 0; q < 4; q++)
                        dst[(size_t)(rb + q) * DD + cc] = f2bf_bits((acc[i][j][q] + bb) * sc);
                } else {
                    const int b_ = rb / SS, s_ = rb % SS;
                    const int h_ = cc >> 6, dd = cc & 63;
                    ushort4 pk;
                    pk.x = f2bf_bits(acc[i][j][0] + bb);
                    pk.y = f2bf_bits(acc[i][j][1] + bb);
                    pk.z = f2bf_bits(acc[i][j][2] + bb);
                    pk.w = f2bf_bits(acc[i][j][3] + bb);
                    *(ushort4*)(vtout + ((size_t)(b_ * HH + h_) * DK + dd) * SS + s_) = pk;
                }
            } else {
                const float bv = bias ? bias[c] : 0.f;
                #pragma unroll
                for (int q = 0; q < 4; q++) {
                    const int r = rb + q;
                    float v = acc[i][j][q] + bv;
                    if (ACT) v = 0.5f * v * (1.0f + erff(v * 0.70710678118654752f));
                    if (RES) v += res[(size_t)r * N + c];
                    if (OUTMODE == 1) ((unsigned short*)Cout)[(size_t)r * N + c] = f2bf_bits(v);
                    else              ((float*)Cout)[(size_t)r * N + c] = v;
                }
            }
        }
    }
}

// ---------------------------------------------------------------------------
// Head GEMM: 256x128 tile, BK=32, 512 threads (8 waves 4x2), DOUBLE-BUFFERED
// LDS + single barrier per K-step, fp32 NT stores. Band swizzle (round-6).
__global__ __launch_bounds__(512) void gemm_head(const unsigned short* __restrict__ A,
                                                 const unsigned short* __restrict__ Bt,
                                                 float* __restrict__ C,
                                                 int M, int N, int K) {
    __shared__ unsigned short As[2][256 * 32];
    __shared__ unsigned short Bs[2][128 * 32];
    const int tid = threadIdx.x;

    // nwg = 250 x 16 = 4000. v = XCD-chunked virtual id (bijective).
    const int f = blockIdx.y * gridDim.x + blockIdx.x;       // 0..3999
    const int v = (f & 7) * 500 + (f >> 3);
    int bx, by;
    if (v < 3840) {                      // 15 full bands of 16 bx
        const int bnd = v >> 8;
        const int r = v & 255;
        by = r >> 4;
        bx = bnd * 16 + (r & 15);
    } else {                             // last band: 10 bx
        const int r = v - 3840;
        by = r / 10;
        bx = 240 + r % 10;
    }
    const int bm = by * 256, bn = bx * 128;

    const int lane = tid & 63;
    const int wave = tid >> 6;
    const int wm = (wave >> 1) * 64;
    const int wn = (wave & 1) * 64;

    f4v acc[4][4];
    #pragma unroll
    for (int i = 0; i < 4; i++)
        #pragma unroll
        for (int j = 0; j < 4; j++)
            acc[i][j] = (f4v){0.f, 0.f, 0.f, 0.f};

    const int arow = tid >> 2;            // 0..127
    const int acol = (tid & 3) * 8;
    const int fr = lane & 15;
    const int fk = (lane >> 4) * 8;

    auto stage = [&](int d, int kt) {
        const int k0 = kt * 32;
        gl_lds16(A + (size_t)(bm + arow) * K + k0 + acol,
                 (char*)(&As[d][0]) + tid * 16);
        gl_lds16(A + (size_t)(bm + 128 + arow) * K + k0 + acol,
                 (char*)(&As[d][0]) + 8192 + tid * 16);
        gl_lds16(Bt + (size_t)(bn + arow) * K + k0 + acol,
                 (char*)(&Bs[d][0]) + tid * 16);
    };

    const int nkt = K / 32;               // 24
    stage(0, 0);
    __syncthreads();

    for (int t = 0; t < nkt; ++t) {
        const int cur = t & 1;
        if (t + 1 < nkt) stage(cur ^ 1, t + 1);

        const unsigned short* Ac = &As[cur][0];
        const unsigned short* Bc = &Bs[cur][0];
        s8v af[4], bf[4];
        #pragma unroll
        for (int i = 0; i < 4; i++)
            af[i] = *(const s8v*)(Ac + (wm + i * 16 + fr) * 32 + fk);
        #pragma unroll
        for (int j = 0; j < 4; j++)
            bf[j] = *(const s8v*)(Bc + (wn + j * 16 + fr) * 32 + fk);
        #pragma unroll
        for (int i = 0; i < 4; i++)
            #pragma unroll
            for (int j = 0; j < 4; j++)
                acc[i][j] = __builtin_amdgcn_mfma_f32_16x16x32_bf16(af[i], bf[j], acc[i][j], 0, 0, 0);
        __syncthreads();
    }

    const int r0 = bm + wm + (lane >> 4) * 4;
    const int c0 = bn + wn + fr;
    #pragma unroll
    for (int i = 0; i < 4; i++) {
        #pragma unroll
        for (int j = 0; j < 4; j++) {
            const int c = c0 + j * 16;
            #pragma unroll
            for (int q = 0; q < 4; q++) {
                const int r = r0 + i * 16 + q;
                __builtin_nontemporal_store(acc[i][j][q], &C[(size_t)r * N + c]);
            }
        }
    }
}

// ---------------------------------------------------------------------------
// Flash attention: QBLK=128 (4 waves x 32 q-rows), KVBLK=128, 1D heavy-first
// grid (bid -> qt = 7 - bid/48, bh = bid%48). K double-buffered in LDS
// (XOR-swizzled); V read directly from vt. No-max softmax (q pre-scaled).
__global__ __launch_bounds__(256) void fattn_kernel(const unsigned short* __restrict__ qb,
                                                    const unsigned short* __restrict__ kb,
                                                    const unsigned short* __restrict__ vt,
                                                    unsigned short* __restrict__ o) {
    __shared__ unsigned short Ks[2][128 * 64];  // [dbuf][key][dk], XOR-swizzled
    __shared__ unsigned short Ps[4][16 * 128];  // per-wave P (one 16-row frag at a time)

    const int bid = blockIdx.x;                 // 0..383
    const int qt = (SS / 128) - 1 - (bid / (BB * HH));   // 7..0, heavy first
    const int bh = bid % (BB * HH);
    const int b = bh / HH, h = bh % HH;
    const int tid = threadIdx.x;
    const int lane = tid & 63;
    const int w = tid >> 6;
    const int fr = lane & 15;
    const int g  = lane >> 4;

    const int krow_ = tid >> 3;                          // 0..31
    const int kcol = ((tid & 7) ^ (krow_ & 7)) * 8;

    const int q0w = qt * 128 + w * 32;
    s8v qf[2][2];
    #pragma unroll
    for (int ri = 0; ri < 2; ri++) {
        const unsigned short* qrow =
            qb + (size_t)(b * SS + q0w + ri * 16 + fr) * DD + h * DK + g * 8;
        qf[ri][0] = *(const s8v*)(qrow);
        qf[ri][1] = *(const s8v*)(qrow + 32);
    }

    f4v ofr[2][4];
    float lrow[2][4];
    #pragma unroll
    for (int ri = 0; ri < 2; ri++)
        #pragma unroll
        for (int z = 0; z < 4; z++) {
            ofr[ri][z] = (f4v){0.f, 0.f, 0.f, 0.f};
            lrow[ri][z] = 0.f;
        }

    unsigned short* Pw = &Ps[w][0];
    const unsigned short* vbh = vt + (size_t)bh * DK * SS;
    const int ktiles = qt + 1;

    auto stagek = [&](int d, int t) {
        const int k0s = t * 128;
        #pragma unroll
        for (int i = 0; i < 4; i++) {
            const int r = i * 32 + krow_;
            gl_lds16(kb + (size_t)(b * SS + k0s + r) * DD + h * DK + kcol,
                     (char*)(&Ks[d][0]) + i * 4096 + tid * 16);
        }
    };

    stagek(0, 0);
    __syncthreads();

    for (int t = 0; t < ktiles; ++t) {
        const int cur = t & 1;
        if (t + 1 < ktiles) stagek(cur ^ 1, t + 1);
        const int k0 = t * 128;
        const char* Kc = (const char*)(&Ks[cur][0]);
        const bool diag = (t == ktiles - 1);

        #pragma unroll
        for (int ri = 0; ri < 2; ri++) {
            const int qloc = w * 32 + ri * 16;   // block-local q row base of this frag
            float rsum[4] = {0.f, 0.f, 0.f, 0.f};
            float p[8][4];
            #pragma unroll
            for (int j = 0; j < 8; j++) {
                const char* kbase = Kc + (j * 16 + fr) * 128;
                s8v b0 = *(const s8v*)(kbase + ((g * 16)      ^ ((fr & 7) << 4)));
                s8v b1 = *(const s8v*)(kbase + ((64 + g * 16) ^ ((fr & 7) << 4)));
                f4v a = (f4v){0.f, 0.f, 0.f, 0.f};
                a = __builtin_amdgcn_mfma_f32_16x16x32_bf16(qf[ri][0], b0, a, 0, 0, 0);
                a = __builtin_amdgcn_mfma_f32_16x16x32_bf16(qf[ri][1], b1, a, 0, 0, 0);
                #pragma unroll
                for (int pq = 0; pq < 4; pq++) {
                    float e = __expf(a[pq]);
                    if (diag && (j * 16 + fr > qloc + g * 4 + pq)) e = 0.f;
                    p[j][pq] = e;
                    rsum[pq] += e;
                }
            }

            #pragma unroll
            for (int off = 1; off < 16; off <<= 1)
                #pragma unroll
                for (int pq = 0; pq < 4; pq++)
                    rsum[pq] += __shfl_xor(rsum[pq], off);
            #pragma unroll
            for (int pq = 0; pq < 4; pq++)
                lrow[ri][pq] += rsum[pq];

            #pragma unroll
            for (int j = 0; j < 8; j++)
                #pragma unroll
                for (int pq = 0; pq < 4; pq++) {
                    const int r = g * 4 + pq;
                    *(unsigned short*)((char*)Pw + r * 256 +
                                       (((j * 16 + fr) * 2) ^ ((r & 7) << 4))) = f2bf_bits(p[j][pq]);
                }

            s8v pa[4];
            #pragma unroll
            for (int ks = 0; ks < 4; ks++)
                pa[ks] = *(const s8v*)((const char*)Pw + fr * 256 +
                                       ((ks * 64 + g * 16) ^ ((fr & 7) << 4)));
            #pragma unroll
            for (int dj = 0; dj < 4; dj++) {
                const unsigned short* vrow = vbh + (size_t)(dj * 16 + fr) * SS + k0;
                #pragma unroll
                for (int ks = 0; ks < 4; ks++) {
                    s8v vv = *(const s8v*)(vrow + ks * 32 + g * 8);
                    ofr[ri][dj] = __builtin_amdgcn_mfma_f32_16x16x32_bf16(pa[ks], vv,
                                                                          ofr[ri][dj], 0, 0, 0);
                }
            }
        }
        __syncthreads();
    }

    #pragma unroll
    for (int ri = 0; ri < 2; ri++)
        #pragma unroll
        for (int pq = 0; pq < 4; pq++) {
            const float inv = 1.0f / lrow[ri][pq];
            const int row_abs = q0w + ri * 16 + g * 4 + pq;
            #pragma unroll
            for (int dj = 0; dj < 4; dj++)
                o[(size_t)(b * SS + row_abs) * DD + h * DK + dj * 16 + fr] =
                    f2bf_bits(ofr[ri][dj][pq] * inv);
        }
}

// ---------------------------------------------------------------------------
extern "C" void kernel_launch(void* const* d_in, const int* in_sizes, int n_in,
                              void* d_out, int out_size, void* d_ws, size_t ws_size,
                              hipStream_t stream) {
    const int*   tokens = (const int*)d_in[0];
    const float* emb    = (const float*)d_in[1];
    const float* Wq     = (const float*)d_in[2];
    const float* bq     = (const float*)d_in[3];
    const float* Wk     = (const float*)d_in[4];
    const float* bk     = (const float*)d_in[5];
    const float* Wv     = (const float*)d_in[6];
    const float* bv     = (const float*)d_in[7];
    const float* Wo     = (const float*)d_in[8];
    const float* bo     = (const float*)d_in[9];
    const float* W1     = (const float*)d_in[10];
    const float* b1     = (const float*)d_in[11];
    const float* W2     = (const float*)d_in[12];
    const float* b2     = (const float*)d_in[13];
    const float* ln1_g  = (const float*)d_in[14];
    const float* ln1_b  = (const float*)d_in[15];
    const float* ln2_g  = (const float*)d_in[16];
    const float* ln2_b  = (const float*)d_in[17];
    const float* lnf_g  = (const float*)d_in[18];
    const float* lnf_b  = (const float*)d_in[19];
    const float* headW  = (const float*)d_in[20];
    float* out = (float*)d_out;
    (void)in_sizes; (void)n_in; (void)out_size; (void)ws_size;

    const size_t MD  = (size_t)MM * DD;
    const size_t MF_ = (size_t)MM * FF;
    const size_t DxD = (size_t)DD * DD;
    const size_t DxF = (size_t)DD * FF;
    const size_t HWs = (size_t)VV * DD;

    char* p = (char*)d_ws;
    float*          x     = (float*)p;          p += MD * 4;
    unsigned short* qb    = (unsigned short*)p; p += MD * 2;
    unsigned short* kbuf  = (unsigned short*)p; p += MD * 2;
    unsigned short* vtb   = (unsigned short*)p; p += MD * 2;
    unsigned short* ao    = (unsigned short*)p; p += MD * 2;
    unsigned short* h     = (unsigned short*)p; p += MD * 2;
    unsigned short* mid   = (unsigned short*)p; p += MF_ * 2;
    unsigned short* wqkvT = (unsigned short*)p; p += 6 * 3 * DxD * 2;
    unsigned short* woT   = (unsigned short*)p; p += 6 * DxD * 2;
    unsigned short* w1T   = (unsigned short*)p; p += 6 * DxF * 2;
    unsigned short* w2T   = (unsigned short*)p; p += 6 * DxF * 2;
    unsigned short* hw    = (unsigned short*)p; p += HWs * 2;

    embed_kernel<<<MM, 256, 0, stream>>>(tokens, emb, x);
    conv_kernel<<<(int)((HWs / 4 + 255) / 256), 256, 0, stream>>>(headW, hw, (long)(HWs / 4));
    prep_kernel<<<6 * 1728, 256, 0, stream>>>(Wq, Wk, Wv, Wo, W1, W2, wqkvT, woT, w1T, w2T);

    const dim3 gQKV(2304 / 128, MM / 128);   // (18, 32)
    const dim3 gDn(DD / 128, MM / 64);       // (6, 64) = 384 blocks for N=768 GEMMs
    const dim3 gF(FF / 128, MM / 128);       // (24, 32)
    const dim3 gHead(VV / 128, MM / 256);    // (250, 16)
    const int  gA = (SS / 128) * BB * HH;    // 384 blocks, 1D heavy-first
    const int  gLN = MM / 4;                 // 1024 blocks, wave-per-row

    for (int l = 0; l < LL; l++) {
        ln_kernel<1><<<gLN, 256, 0, stream>>>(x, ln1_g + l * DD, ln1_b + l * DD, h);
        gemm_mfma<128, 128, 2, 2, 0, 0, 3><<<gQKV, 256, 0, stream>>>(
            h, wqkvT + (size_t)l * 3 * DxD, bq + l * DD, nullptr, qb, MM, 2304, DD,
            bk + l * DD, bv + l * DD, kbuf, vtb);
        fattn_kernel<<<gA, 256, 0, stream>>>(qb, kbuf, vtb, ao);
        gemm_mfma<64, 128, 1, 4, 0, 1, 0><<<gDn, 256, 0, stream>>>(
            ao, woT + (size_t)l * DxD, bo + l * DD, x, x, MM, DD, DD,
            nullptr, nullptr, nullptr, nullptr);
        ln_kernel<1><<<gLN, 256, 0, stream>>>(x, ln2_g + l * DD, ln2_b + l * DD, h);
        gemm_mfma<128, 128, 2, 2, 1, 0, 1><<<gF, 256, 0, stream>>>(
            h, w1T + (size_t)l * DxF, b1 + l * FF, nullptr, mid, MM, FF, DD,
            nullptr, nullptr, nullptr, nullptr);
        gemm_mfma<64, 128, 1, 4, 0, 1, 0><<<gDn, 256, 0, stream>>>(
            mid, w2T + (size_t)l * DxF, b2 + l * DD, x, x, MM, DD, FF,
            nullptr, nullptr, nullptr, nullptr);
    }

    ln_kernel<1><<<gLN, 256, 0, stream>>>(x, lnf_g, lnf_b, h);
    gemm_head<<<gHead, 512, 0, stream>>>(h, hw, out, MM, VV, DD);
}

// Round 14
// 1674.999 us; speedup vs baseline: 1.0321x; 1.0321x over previous
//
#include <hip/hip_runtime.h>
#include <hip/hip_bf16.h>
#include <math.h>

// Problem constants
#define BB 4
#define SS 1024
#define DD 768
#define HH 12
#define LL 6
#define FF 3072
#define VV 32000
#define DK 64
#define MM (BB * SS)   // 4096 rows

typedef __attribute__((ext_vector_type(8))) short s8v;   // 8 bf16 (4 VGPRs)
typedef __attribute__((ext_vector_type(4))) float f4v;   // 4 fp32 acc

__device__ inline unsigned short f2bf_bits(float f) {
    unsigned u = __builtin_bit_cast(unsigned, f);
    unsigned r = (u + 0x7fffu + ((u >> 16) & 1u)) >> 16;
    return (unsigned short)r;
}

__device__ inline void gl_lds16(const void* g, void* l) {
    __builtin_amdgcn_global_load_lds((const __attribute__((address_space(1))) void*)g,
                                     (__attribute__((address_space(3))) void*)l, 16, 0, 0);
}

// ---------------------------------------------------------------------------
__global__ void embed_kernel(const int* __restrict__ tokens,
                             const float* __restrict__ emb,
                             float* __restrict__ x) {
    const int row = blockIdx.x;
    const int s = row % SS;
    const int tok = tokens[row];
    const float* er = emb + (size_t)tok * DD;
    float* xr = x + (size_t)row * DD;
    const float neg_ln_base = -logf(10000.0f) / (float)DD;
    for (int d = threadIdx.x; d < DD; d += blockDim.x) {
        int i2 = d & ~1;
        float div = expf((float)i2 * neg_ln_base);
        float ang = (float)s * div;
        float pe = (d & 1) ? cosf(ang) : sinf(ang);
        xr[d] = er[d] + pe;
    }
}

// ---------------------------------------------------------------------------
// LayerNorm: one WAVE per row (4 rows / 256-block), shuffle-only reduce.
template <int OUTBF>
__global__ __launch_bounds__(256) void ln_kernel(const float* __restrict__ x,
                                                 const float* __restrict__ g,
                                                 const float* __restrict__ b,
                                                 void* __restrict__ outp) {
    const int row = blockIdx.x * 4 + (threadIdx.x >> 6);
    const int lane = threadIdx.x & 63;
    const float* xr = x + (size_t)row * DD;

    float4 v[3];
    float s = 0.f, s2 = 0.f;
    #pragma unroll
    for (int j = 0; j < 3; j++) {
        v[j] = *(const float4*)(xr + j * 256 + lane * 4);
        s  += v[j].x + v[j].y + v[j].z + v[j].w;
        s2 += v[j].x * v[j].x + v[j].y * v[j].y + v[j].z * v[j].z + v[j].w * v[j].w;
    }
    #pragma unroll
    for (int off = 32; off; off >>= 1) {
        s  += __shfl_xor(s, off);
        s2 += __shfl_xor(s2, off);
    }
    const float mu = s / (float)DD;
    const float var = s2 / (float)DD - mu * mu;
    const float r = rsqrtf(var + 1e-5f);

    #pragma unroll
    for (int j = 0; j < 3; j++) {
        const int c = j * 256 + lane * 4;
        const float4 gv = *(const float4*)(g + c);
        const float4 bv = *(const float4*)(b + c);
        float o0 = (v[j].x - mu) * r * gv.x + bv.x;
        float o1 = (v[j].y - mu) * r * gv.y + bv.y;
        float o2 = (v[j].z - mu) * r * gv.z + bv.z;
        float o3 = (v[j].w - mu) * r * gv.w + bv.w;
        if (OUTBF) {
            ushort4 o;
            o.x = f2bf_bits(o0); o.y = f2bf_bits(o1);
            o.z = f2bf_bits(o2); o.w = f2bf_bits(o3);
            *(ushort4*)((unsigned short*)outp + (size_t)row * DD + c) = o;
        } else {
            float4 o = {o0, o1, o2, o3};
            *(float4*)((float*)outp + (size_t)row * DD + c) = o;
        }
    }
}

// ---------------------------------------------------------------------------
// ALL-layer weight prep in one launch: 6 layers x 1728 tiles.
__global__ __launch_bounds__(256) void prep_kernel(const float* __restrict__ Wq,
                                                   const float* __restrict__ Wk,
                                                   const float* __restrict__ Wv,
                                                   const float* __restrict__ Wo,
                                                   const float* __restrict__ W1,
                                                   const float* __restrict__ W2,
                                                   unsigned short* __restrict__ wqkvT,
                                                   unsigned short* __restrict__ woT,
                                                   unsigned short* __restrict__ w1T,
                                                   unsigned short* __restrict__ w2T) {
    const size_t DxD = (size_t)DD * DD, DxF = (size_t)DD * FF;
    const int lid = blockIdx.x / 1728;
    const int id  = blockIdx.x % 1728;
    const float* src; unsigned short* dst; int R, C, t;
    if (id < 432)       { int seg = id / 144; t = id % 144;
                          src = (seg == 0 ? Wq : seg == 1 ? Wk : Wv) + lid * DxD;
                          dst = wqkvT + lid * 3 * DxD + (size_t)seg * DxD; R = DD; C = DD; }
    else if (id < 576)  { t = id - 432; src = Wo + lid * DxD; dst = woT + lid * DxD; R = DD; C = DD; }
    else if (id < 1152) { t = id - 576;  src = W1 + lid * DxF; dst = w1T + lid * DxF; R = DD; C = FF; }
    else                { t = id - 1152; src = W2 + lid * DxF; dst = w2T + lid * DxF; R = FF; C = DD; }
    const int tilesC = C / 64;
    const int r0 = (t / tilesC) * 64, c0 = (t % tilesC) * 64;
    __shared__ float tb[64][65];
    const int lr = threadIdx.x >> 6, lc = threadIdx.x & 63;
    #pragma unroll
    for (int it = 0; it < 16; ++it) {
        int r = it * 4 + lr;
        tb[r][lc] = src[(size_t)(r0 + r) * C + c0 + lc];
    }
    __syncthreads();
    #pragma unroll
    for (int it = 0; it < 16; ++it) {
        int c = it * 4 + lr;
        dst[(size_t)(c0 + c) * R + r0 + lc] = f2bf_bits(tb[lc][c]);
    }
}

__global__ __launch_bounds__(256) void conv_kernel(const float* __restrict__ in,
                                                   unsigned short* __restrict__ out,
                                                   long n4) {
    long i = (long)blockIdx.x * 256 + threadIdx.x;
    if (i < n4) {
        float4 v = ((const float4*)in)[i];
        ushort4 o;
        o.x = f2bf_bits(v.x); o.y = f2bf_bits(v.y);
        o.z = f2bf_bits(v.z); o.w = f2bf_bits(v.w);
        ((ushort4*)out)[i] = o;
    }
}

// ---------------------------------------------------------------------------
// bf16 MFMA GEMM, BK=32, DOUBLE-BUFFERED LDS (round-11 proven) + T5 setprio
// around the MFMA cluster (dbuf schedule gives wave role-diversity).
// OUTMODE: 0 fp32 [M,N]; 1 bf16 [M,N]; 3 fused-QKV split (needs BM=BN=128).
// OUTMODE 3: q output pre-scaled by 1/sqrt(dk)=0.125 (consumed only by fattn).
template <int BM, int BN, int WGM, int WGN, int ACT, int RES, int OUTMODE>
__global__ __launch_bounds__(256) void gemm_mfma(const unsigned short* __restrict__ A,
                                                 const unsigned short* __restrict__ Bt,
                                                 const float* __restrict__ bias,
                                                 const float* res,
                                                 void* Cout, int M, int N, int K,
                                                 const float* biasK, const float* biasV,
                                                 unsigned short* kout, unsigned short* vtout) {
    __shared__ unsigned short As[2][BM * 32];
    __shared__ unsigned short Bs[2][BN * 32];
    constexpr int MF = (BM / WGM) / 16;
    constexpr int NF = (BN / WGN) / 16;
    const int tid = threadIdx.x;
    const int bm = blockIdx.y * BM, bn = blockIdx.x * BN;
    const int lane = tid & 63;
    const int wave = tid >> 6;
    const int wr = (wave / WGN) * (BM / WGM);
    const int wc = (wave % WGN) * (BN / WGN);

    f4v acc[MF][NF];
    #pragma unroll
    for (int i = 0; i < MF; i++)
        #pragma unroll
        for (int j = 0; j < NF; j++)
            acc[i][j] = (f4v){0.f, 0.f, 0.f, 0.f};

    const int arow = tid >> 2;        // 0..63
    const int acol = (tid & 3) * 8;
    const int fr = lane & 15;
    const int fk = (lane >> 4) * 8;

    auto stage = [&](int d, int kt) {
        const int k0 = kt * 32;
        #pragma unroll
        for (int i = 0; i < BM / 64; i++)
            gl_lds16(A + (size_t)(bm + i * 64 + arow) * K + k0 + acol,
                     (char*)(&As[d][0]) + i * 4096 + tid * 16);
        #pragma unroll
        for (int i = 0; i < BN / 64; i++)
            gl_lds16(Bt + (size_t)(bn + i * 64 + arow) * K + k0 + acol,
                     (char*)(&Bs[d][0]) + i * 4096 + tid * 16);
    };

    const int nkt = K / 32;
    stage(0, 0);
    __syncthreads();

    for (int t = 0; t < nkt; ++t) {
        const int cur = t & 1;
        if (t + 1 < nkt) stage(cur ^ 1, t + 1);

        const unsigned short* Ac = &As[cur][0];
        const unsigned short* Bc = &Bs[cur][0];
        s8v af[MF], bf[NF];
        #pragma unroll
        for (int i = 0; i < MF; i++)
            af[i] = *(const s8v*)(Ac + (wr + i * 16 + fr) * 32 + fk);
        #pragma unroll
        for (int j = 0; j < NF; j++)
            bf[j] = *(const s8v*)(Bc + (wc + j * 16 + fr) * 32 + fk);
        __builtin_amdgcn_s_setprio(1);
        #pragma unroll
        for (int i = 0; i < MF; i++)
            #pragma unroll
            for (int j = 0; j < NF; j++)
                acc[i][j] = __builtin_amdgcn_mfma_f32_16x16x32_bf16(af[i], bf[j], acc[i][j], 0, 0, 0);
        __builtin_amdgcn_s_setprio(0);
        __syncthreads();
    }

    const int r0 = bm + wr + (lane >> 4) * 4;
    const int c0 = bn + wc + fr;
    #pragma unroll
    for (int i = 0; i < MF; i++) {
        const int rb = r0 + i * 16;
        #pragma unroll
        for (int j = 0; j < NF; j++) {
            const int c = c0 + j * 16;
            if (OUTMODE == 3) {
                const int seg = (c >= 1536) ? 2 : (c >= 768 ? 1 : 0);
                const int cc = c - seg * 768;
                const float bb = (seg == 0 ? bias[cc] : seg == 1 ? biasK[cc] : biasV[cc]);
                if (seg < 2) {
                    unsigned short* dst = (seg == 0 ? (unsigned short*)Cout : kout);
                    const float sc = (seg == 0) ? 0.125f : 1.0f;   // pre-scale q by 1/sqrt(dk)
                    #pragma unroll
                    for (int q = 0; q < 4; q++)
                        dst[(size_t)(rb + q) * DD + cc] = f2bf_bits((acc[i][j][q] + bb) * sc);
                } else {
                    const int b_ = rb / SS, s_ = rb % SS;
                    const int h_ = cc >> 6, dd = cc & 63;
                    ushort4 pk;
                    pk.x = f2bf_bits(acc[i][j][0] + bb);
                    pk.y = f2bf_bits(acc[i][j][1] + bb);
                    pk.z = f2bf_bits(acc[i][j][2] + bb);
                    pk.w = f2bf_bits(acc[i][j][3] + bb);
                    *(ushort4*)(vtout + ((size_t)(b_ * HH + h_) * DK + dd) * SS + s_) = pk;
                }
            } else {
                const float bv = bias ? bias[c] : 0.f;
                #pragma unroll
                for (int q = 0; q < 4; q++) {
                    const int r = rb + q;
                    float v = acc[i][j][q] + bv;
                    if (ACT) v = 0.5f * v * (1.0f + erff(v * 0.70710678118654752f));
                    if (RES) v += res[(size_t)r * N + c];
                    if (OUTMODE == 1) ((unsigned short*)Cout)[(size_t)r * N + c] = f2bf_bits(v);
                    else              ((float*)Cout)[(size_t)r * N + c] = v;
                }
            }
        }
    }
}

// ---------------------------------------------------------------------------
// Head GEMM: 256x128 tile, BK=32, 512 threads (8 waves 4x2), DOUBLE-BUFFERED
// LDS + single barrier per K-step + T5 setprio, fp32 NT stores. Band swizzle.
__global__ __launch_bounds__(512) void gemm_head(const unsigned short* __restrict__ A,
                                                 const unsigned short* __restrict__ Bt,
                                                 float* __restrict__ C,
                                                 int M, int N, int K) {
    __shared__ unsigned short As[2][256 * 32];
    __shared__ unsigned short Bs[2][128 * 32];
    const int tid = threadIdx.x;

    // nwg = 250 x 16 = 4000. v = XCD-chunked virtual id (bijective).
    const int f = blockIdx.y * gridDim.x + blockIdx.x;       // 0..3999
    const int v = (f & 7) * 500 + (f >> 3);
    int bx, by;
    if (v < 3840) {                      // 15 full bands of 16 bx
        const int bnd = v >> 8;
        const int r = v & 255;
        by = r >> 4;
        bx = bnd * 16 + (r & 15);
    } else {                             // last band: 10 bx
        const int r = v - 3840;
        by = r / 10;
        bx = 240 + r % 10;
    }
    const int bm = by * 256, bn = bx * 128;

    const int lane = tid & 63;
    const int wave = tid >> 6;
    const int wm = (wave >> 1) * 64;
    const int wn = (wave & 1) * 64;

    f4v acc[4][4];
    #pragma unroll
    for (int i = 0; i < 4; i++)
        #pragma unroll
        for (int j = 0; j < 4; j++)
            acc[i][j] = (f4v){0.f, 0.f, 0.f, 0.f};

    const int arow = tid >> 2;            // 0..127
    const int acol = (tid & 3) * 8;
    const int fr = lane & 15;
    const int fk = (lane >> 4) * 8;

    auto stage = [&](int d, int kt) {
        const int k0 = kt * 32;
        gl_lds16(A + (size_t)(bm + arow) * K + k0 + acol,
                 (char*)(&As[d][0]) + tid * 16);
        gl_lds16(A + (size_t)(bm + 128 + arow) * K + k0 + acol,
                 (char*)(&As[d][0]) + 8192 + tid * 16);
        gl_lds16(Bt + (size_t)(bn + arow) * K + k0 + acol,
                 (char*)(&Bs[d][0]) + tid * 16);
    };

    const int nkt = K / 32;               // 24
    stage(0, 0);
    __syncthreads();

    for (int t = 0; t < nkt; ++t) {
        const int cur = t & 1;
        if (t + 1 < nkt) stage(cur ^ 1, t + 1);

        const unsigned short* Ac = &As[cur][0];
        const unsigned short* Bc = &Bs[cur][0];
        s8v af[4], bf[4];
        #pragma unroll
        for (int i = 0; i < 4; i++)
            af[i] = *(const s8v*)(Ac + (wm + i * 16 + fr) * 32 + fk);
        #pragma unroll
        for (int j = 0; j < 4; j++)
            bf[j] = *(const s8v*)(Bc + (wn + j * 16 + fr) * 32 + fk);
        __builtin_amdgcn_s_setprio(1);
        #pragma unroll
        for (int i = 0; i < 4; i++)
            #pragma unroll
            for (int j = 0; j < 4; j++)
                acc[i][j] = __builtin_amdgcn_mfma_f32_16x16x32_bf16(af[i], bf[j], acc[i][j], 0, 0, 0);
        __builtin_amdgcn_s_setprio(0);
        __syncthreads();
    }

    const int r0 = bm + wm + (lane >> 4) * 4;
    const int c0 = bn + wn + fr;
    #pragma unroll
    for (int i = 0; i < 4; i++) {
        #pragma unroll
        for (int j = 0; j < 4; j++) {
            const int c = c0 + j * 16;
            #pragma unroll
            for (int q = 0; q < 4; q++) {
                const int r = r0 + i * 16 + q;
                __builtin_nontemporal_store(acc[i][j][q], &C[(size_t)r * N + c]);
            }
        }
    }
}

// ---------------------------------------------------------------------------
// Flash attention (round-12 proven): block = (qtile 64 rows, b*H), 4 waves x
// 16 q-rows, KVBLK=128. K double-buffered in LDS (XOR-swizzled). V direct.
// No-max softmax (q pre-scaled by 1/sqrt(dk) in QKV epilogue).
__global__ __launch_bounds__(256) void fattn_kernel(const unsigned short* __restrict__ qb,
                                                    const unsigned short* __restrict__ kb,
                                                    const unsigned short* __restrict__ vt,
                                                    unsigned short* __restrict__ o) {
    __shared__ unsigned short Ks[2][128 * 64];  // [dbuf][key][dk], XOR-swizzled
    __shared__ unsigned short Ps[4][16 * 128];  // per-wave P

    const int qt = (int)gridDim.x - 1 - (int)blockIdx.x;   // heavy tiles first
    const int bh = blockIdx.y;
    const int b = bh / HH, h = bh % HH;
    const int tid = threadIdx.x;
    const int lane = tid & 63;
    const int w = tid >> 6;
    const int fr = lane & 15;
    const int g  = lane >> 4;

    const int krow_ = tid >> 3;                          // 0..31
    const int kcol = ((tid & 7) ^ (krow_ & 7)) * 8;

    const int q0w = qt * 64 + w * 16;
    s8v qf[2];
    {
        const unsigned short* qrow = qb + (size_t)(b * SS + q0w + fr) * DD + h * DK + g * 8;
        qf[0] = *(const s8v*)(qrow);
        qf[1] = *(const s8v*)(qrow + 32);
    }

    f4v ofr[4];
    #pragma unroll
    for (int dj = 0; dj < 4; dj++) ofr[dj] = (f4v){0.f, 0.f, 0.f, 0.f};
    float lrow[4] = {0.f, 0.f, 0.f, 0.f};

    unsigned short* Pw = &Ps[w][0];
    const unsigned short* vbh = vt + (size_t)bh * DK * SS;
    const int ktiles = qt / 2 + 1;

    auto stagek = [&](int d, int t) {
        const int k0s = t * 128;
        #pragma unroll
        for (int i = 0; i < 4; i++) {
            const int r = i * 32 + krow_;
            gl_lds16(kb + (size_t)(b * SS + k0s + r) * DD + h * DK + kcol,
                     (char*)(&Ks[d][0]) + i * 4096 + tid * 16);
        }
    };

    stagek(0, 0);
    __syncthreads();

    for (int t = 0; t < ktiles; ++t) {
        const int cur = t & 1;
        if (t + 1 < ktiles) stagek(cur ^ 1, t + 1);
        const int k0 = t * 128;
        const char* Kc = (const char*)(&Ks[cur][0]);

        const bool diag = (t == ktiles - 1);
        float rsum[4] = {0.f, 0.f, 0.f, 0.f};
        float p[8][4];
        #pragma unroll
        for (int j = 0; j < 8; j++) {
            const char* kbase = Kc + (j * 16 + fr) * 128;
            s8v b0 = *(const s8v*)(kbase + ((g * 16)      ^ ((fr & 7) << 4)));
            s8v b1 = *(const s8v*)(kbase + ((64 + g * 16) ^ ((fr & 7) << 4)));
            f4v a = (f4v){0.f, 0.f, 0.f, 0.f};
            a = __builtin_amdgcn_mfma_f32_16x16x32_bf16(qf[0], b0, a, 0, 0, 0);
            a = __builtin_amdgcn_mfma_f32_16x16x32_bf16(qf[1], b1, a, 0, 0, 0);
            #pragma unroll
            for (int pq = 0; pq < 4; pq++) {
                float e = __expf(a[pq]);
                if (diag && (k0 + j * 16 + fr > q0w + g * 4 + pq)) e = 0.f;
                p[j][pq] = e;
                rsum[pq] += e;
            }
        }

        #pragma unroll
        for (int off = 1; off < 16; off <<= 1)
            #pragma unroll
            for (int pq = 0; pq < 4; pq++)
                rsum[pq] += __shfl_xor(rsum[pq], off);
        #pragma unroll
        for (int pq = 0; pq < 4; pq++)
            lrow[pq] += rsum[pq];

        #pragma unroll
        for (int j = 0; j < 8; j++)
            #pragma unroll
            for (int pq = 0; pq < 4; pq++) {
                const int r = g * 4 + pq;
                *(unsigned short*)((char*)Pw + r * 256 +
                                   (((j * 16 + fr) * 2) ^ ((r & 7) << 4))) = f2bf_bits(p[j][pq]);
            }

        s8v pa[4];
        #pragma unroll
        for (int ks = 0; ks < 4; ks++)
            pa[ks] = *(const s8v*)((const char*)Pw + fr * 256 +
                                   ((ks * 64 + g * 16) ^ ((fr & 7) << 4)));
        #pragma unroll
        for (int dj = 0; dj < 4; dj++) {
            const unsigned short* vrow = vbh + (size_t)(dj * 16 + fr) * SS + k0;
            #pragma unroll
            for (int ks = 0; ks < 4; ks++) {
                s8v vv = *(const s8v*)(vrow + ks * 32 + g * 8);
                ofr[dj] = __builtin_amdgcn_mfma_f32_16x16x32_bf16(pa[ks], vv, ofr[dj], 0, 0, 0);
            }
        }
        __syncthreads();
    }

    #pragma unroll
    for (int pq = 0; pq < 4; pq++) {
        const float inv = 1.0f / lrow[pq];
        const int row_abs = q0w + g * 4 + pq;
        #pragma unroll
        for (int dj = 0; dj < 4; dj++)
            o[(size_t)(b * SS + row_abs) * DD + h * DK + dj * 16 + fr] =
                f2bf_bits(ofr[dj][pq] * inv);
    }
}

// ---------------------------------------------------------------------------
extern "C" void kernel_launch(void* const* d_in, const int* in_sizes, int n_in,
                              void* d_out, int out_size, void* d_ws, size_t ws_size,
                              hipStream_t stream) {
    const int*   tokens = (const int*)d_in[0];
    const float* emb    = (const float*)d_in[1];
    const float* Wq     = (const float*)d_in[2];
    const float* bq     = (const float*)d_in[3];
    const float* Wk     = (const float*)d_in[4];
    const float* bk     = (const float*)d_in[5];
    const float* Wv     = (const float*)d_in[6];
    const float* bv     = (const float*)d_in[7];
    const float* Wo     = (const float*)d_in[8];
    const float* bo     = (const float*)d_in[9];
    const float* W1     = (const float*)d_in[10];
    const float* b1     = (const float*)d_in[11];
    const float* W2     = (const float*)d_in[12];
    const float* b2     = (const float*)d_in[13];
    const float* ln1_g  = (const float*)d_in[14];
    const float* ln1_b  = (const float*)d_in[15];
    const float* ln2_g  = (const float*)d_in[16];
    const float* ln2_b  = (const float*)d_in[17];
    const float* lnf_g  = (const float*)d_in[18];
    const float* lnf_b  = (const float*)d_in[19];
    const float* headW  = (const float*)d_in[20];
    float* out = (float*)d_out;
    (void)in_sizes; (void)n_in; (void)out_size; (void)ws_size;

    const size_t MD  = (size_t)MM * DD;
    const size_t MF_ = (size_t)MM * FF;
    const size_t DxD = (size_t)DD * DD;
    const size_t DxF = (size_t)DD * FF;
    const size_t HWs = (size_t)VV * DD;

    char* p = (char*)d_ws;
    float*          x     = (float*)p;          p += MD * 4;
    unsigned short* qb    = (unsigned short*)p; p += MD * 2;
    unsigned short* kbuf  = (unsigned short*)p; p += MD * 2;
    unsigned short* vtb   = (unsigned short*)p; p += MD * 2;
    unsigned short* ao    = (unsigned short*)p; p += MD * 2;
    unsigned short* h     = (unsigned short*)p; p += MD * 2;
    unsigned short* mid   = (unsigned short*)p; p += MF_ * 2;
    unsigned short* wqkvT = (unsigned short*)p; p += 6 * 3 * DxD * 2;
    unsigned short* woT   = (unsigned short*)p; p += 6 * DxD * 2;
    unsigned short* w1T   = (unsigned short*)p; p += 6 * DxF * 2;
    unsigned short* w2T   = (unsigned short*)p; p += 6 * DxF * 2;
    unsigned short* hw    = (unsigned short*)p; p += HWs * 2;

    embed_kernel<<<MM, 256, 0, stream>>>(tokens, emb, x);
    conv_kernel<<<(int)((HWs / 4 + 255) / 256), 256, 0, stream>>>(headW, hw, (long)(HWs / 4));
    prep_kernel<<<6 * 1728, 256, 0, stream>>>(Wq, Wk, Wv, Wo, W1, W2, wqkvT, woT, w1T, w2T);

    const dim3 gQKV(2304 / 128, MM / 128);   // (18, 32)
    const dim3 gDn(DD / 128, MM / 64);       // (6, 64) = 384 blocks for N=768 GEMMs
    const dim3 gF(FF / 128, MM / 128);       // (24, 32)
    const dim3 gHead(VV / 128, MM / 256);    // (250, 16)
    const dim3 gA(SS / 64, BB * HH);         // (16, 48)
    const int  gLN = MM / 4;                 // 1024 blocks, wave-per-row

    for (int l = 0; l < LL; l++) {
        ln_kernel<1><<<gLN, 256, 0, stream>>>(x, ln1_g + l * DD, ln1_b + l * DD, h);
        gemm_mfma<128, 128, 2, 2, 0, 0, 3><<<gQKV, 256, 0, stream>>>(
            h, wqkvT + (size_t)l * 3 * DxD, bq + l * DD, nullptr, qb, MM, 2304, DD,
            bk + l * DD, bv + l * DD, kbuf, vtb);
        fattn_kernel<<<gA, 256, 0, stream>>>(qb, kbuf, vtb, ao);
        gemm_mfma<64, 128, 1, 4, 0, 1, 0><<<gDn, 256, 0, stream>>>(
            ao, woT + (size_t)l * DxD, bo + l * DD, x, x, MM, DD, DD,
            nullptr, nullptr, nullptr, nullptr);
        ln_kernel<1><<<gLN, 256, 0, stream>>>(x, ln2_g + l * DD, ln2_b + l * DD, h);
        gemm_mfma<128, 128, 2, 2, 1, 0, 1><<<gF, 256, 0, stream>>>(
            h, w1T + (size_t)l * DxF, b1 + l * FF, nullptr, mid, MM, FF, DD,
            nullptr, nullptr, nullptr, nullptr);
        gemm_mfma<64, 128, 1, 4, 0, 1, 0><<<gDn, 256, 0, stream>>>(
            mid, w2T + (size_t)l * DxF, b2 + l * DD, x, x, MM, DD, FF,
            nullptr, nullptr, nullptr, nullptr);
    }

    ln_kernel<1><<<gLN, 256, 0, stream>>>(x, lnf_g, lnf_b, h);
    gemm_head<<<gHead, 512, 0, stream>>>(h, hw, out, MM, VV, DD);
}